// Round 6
// baseline (742.372 us; speedup 1.0000x reference)
//
#include <hip/hip_runtime.h>
#include <hip/hip_bf16.h>
#include <hip/hip_cooperative_groups.h>

namespace cg = cooperative_groups;

// GCN_85804856639970 — 2-layer GCN + FC head, MI355X.
// N=50000, E=800000, 128->128->64, head 64x64. fp32 in/out, edge_index int32.
//
// R18 = R17 (176 us) collapsed into ONE cooperative mega-kernel.
// Evidence: R14 (7 dispatches, sum~160, meas 226), R15 (5, ~156, 209),
// R17 (5, ~135, 176) all fit ~9-10 us of overhead per dispatch boundary;
// top-5 counters now show only harness reset fills (44 us) -> every kernel
// of ours is <44 us and ~45 us of the budget is inter-dispatch dead time.
// Phases (grid.sync + threadfence between):
//  P0 weight transpose + gcnt zero + sentinel rows
//  P1 gemm1 (782 one-tile units, 17KB LDS each) || edge binning (98 chunks)
//  P2 bucket-exclusive scatter -> sentinel-padded col + cnt + dinv
//  P3 full-grid in-place hs1r dinv prescale (was 196-block-limited)
//  P4 agg128 (serial-pair, 52-VGPR form: 4 blk/CU x 4 waves co-resident
//     beats R17's VGPR-heavy dual-pair) + fused @W2 -> hs2 (prescaled)
//  P5 agg64 + fused FC head -> out
// Grid = occupancy-checked blocks/CU x 256 CUs; LDS union 33 KB.
// Numerics identical to R17 (absmax 0.001953125). N <= 65535 required.

typedef __attribute__((ext_vector_type(8))) short bf16x8;
typedef __attribute__((ext_vector_type(4))) float f32x4;

#define SLAB 64
#define BCAP 6144
#define BINCH 8192
#define SMEM_BYTES 33792  // max(gemm 17408, bin 3072, scatter 33792, agg 4480)

__device__ __forceinline__ unsigned short f2bf(float f) {
    unsigned u = __float_as_uint(f);
    unsigned r = (u + 0x7FFFu + ((u >> 16) & 1u)) >> 16;
    return (unsigned short)r;
}
__device__ __forceinline__ float bf16_lo(unsigned u) {
    return __uint_as_float((u & 0xFFFFu) << 16);
}
__device__ __forceinline__ float bf16_hi(unsigned u) {
    return __uint_as_float(u & 0xFFFF0000u);
}

#define UNPK16(cA, cB, ci)                                        \
    ci[0] = cA.x & 0xFFFFu;  ci[1] = cA.x >> 16;                  \
    ci[2] = cA.y & 0xFFFFu;  ci[3] = cA.y >> 16;                  \
    ci[4] = cA.z & 0xFFFFu;  ci[5] = cA.z >> 16;                  \
    ci[6] = cA.w & 0xFFFFu;  ci[7] = cA.w >> 16;                  \
    ci[8] = cB.x & 0xFFFFu;  ci[9] = cB.x >> 16;                  \
    ci[10] = cB.y & 0xFFFFu; ci[11] = cB.y >> 16;                 \
    ci[12] = cB.z & 0xFFFFu; ci[13] = cB.z >> 16;                 \
    ci[14] = cB.w & 0xFFFFu; ci[15] = cB.w >> 16;

struct MegaParams {
    const int* src; const int* dst;
    int e, n, nb, nbin, ngt, nagg;
    int* gcnt; unsigned* staging; int* cnt; float* dinv;
    unsigned short* col;
    const float* x; const float* W1; const float* W2; const float* fcW;
    const float* b1; const float* b2; const float* fcb;
    unsigned short* W1T; unsigned short* W2T; unsigned short* fcWT;
    unsigned short* hs1r; unsigned short* hs2;
    float* out;
};

// ---- P1a: one 64-row tile of bf16(X[128] @ W1) ----
__device__ __forceinline__ void gemm1_tile(const MegaParams& P, int blk, int tid,
                                           unsigned short* xs) {
    constexpr int LDW = 136;
    int base = blk * 64;
    for (int idx = tid; idx < 64 * 32; idx += 256) {
        int r = idx >> 5, c = idx & 31;
        int row = base + r;
        float4 v = make_float4(0.f, 0.f, 0.f, 0.f);
        if (row < P.n) v = ((const float4*)P.x)[(size_t)row * 32 + c];
        unsigned short* dp = &xs[r * LDW + c * 4];
        dp[0] = f2bf(v.x); dp[1] = f2bf(v.y); dp[2] = f2bf(v.z); dp[3] = f2bf(v.w);
    }
    __syncthreads();

    int wave = tid >> 6, lane = tid & 63;
    int quad = lane >> 4, l16 = lane & 15;
    int rbase = wave * 16;

    bf16x8 af[4];
#pragma unroll
    for (int kb = 0; kb < 4; ++kb)
        af[kb] = *(const bf16x8*)&xs[(rbase + l16) * LDW + kb * 32 + quad * 8];

#pragma unroll
    for (int jt = 0; jt < 8; ++jt) {
        f32x4 acc = {0.f, 0.f, 0.f, 0.f};
#pragma unroll
        for (int kb = 0; kb < 4; ++kb) {
            bf16x8 bf = *(const bf16x8*)&P.W1T[(size_t)(jt * 16 + l16) * 128 + kb * 32 + quad * 8];
            acc = __builtin_amdgcn_mfma_f32_16x16x32_bf16(af[kb], bf, acc, 0, 0, 0);
        }
#pragma unroll
        for (int r = 0; r < 4; ++r) {
            int row = base + rbase + quad * 4 + r;
            if (row < P.n)
                P.hs1r[(size_t)row * 128 + jt * 16 + l16] = f2bf(acc[r]);
        }
    }
}

// ---- P1b: bin one 8192-edge chunk into per-bucket staging ----
__device__ __forceinline__ void bin_chunk(const MegaParams& P, int b0, int tid,
                                          int* bcnt) {
    int* bpos = bcnt + 256;
    int* gofs = bcnt + 512;
    bcnt[tid] = 0; bpos[tid] = 0;
    __syncthreads();
    int e0 = b0 * BINCH;
    int lim = P.e - e0; if (lim > BINCH) lim = BINCH;
    for (int i = tid; i < lim; i += 256)
        atomicAdd(&bcnt[P.dst[e0 + i] >> 8], 1);
    __syncthreads();
    if (tid < P.nb) {
        int c = bcnt[tid];
        gofs[tid] = c ? atomicAdd(&P.gcnt[tid], c) : 0;
    }
    __syncthreads();
    for (int i = tid; i < lim; i += 256) {
        int d = P.dst[e0 + i], s = P.src[e0 + i];
        int b = d >> 8;
        int pp = atomicAdd(&bpos[b], 1);
        int idx = gofs[b] + pp;
        if (idx < BCAP)
            P.staging[(size_t)b * BCAP + idx] = ((unsigned)d << 16) | (unsigned)s;
    }
}

// ---- P2: scatter one bucket into sentinel-padded col + cnt + dinv ----
__device__ __forceinline__ void scatter_bucket(const MegaParams& P, int b, int tid,
                                               unsigned char* smem) {
    int* lcnt = (int*)smem;
    unsigned short* ls = (unsigned short*)(smem + 1024);
    lcnt[tid] = 0;
    unsigned sent2 = (unsigned)P.n | ((unsigned)P.n << 16);
    for (int i = tid; i < 8192; i += 256) ((unsigned*)ls)[i] = sent2;
    __syncthreads();
    int eb = P.gcnt[b]; if (eb > BCAP) eb = BCAP;
    const unsigned* sp = P.staging + (size_t)b * BCAP;
    for (int i = tid; i < eb; i += 256) {
        unsigned pk = sp[i];
        int dl = (int)(pk >> 16) & 255;
        int pos = atomicAdd(&lcnt[dl], 1);
        if (pos < SLAB) ls[(dl << 6) + pos] = (unsigned short)(pk & 0xFFFFu);
    }
    __syncthreads();
    int base = b << 8;
    const uint4* lsv = (const uint4*)ls;
    uint4* gv = (uint4*)(P.col + ((size_t)base << 6));
    for (int i = tid; i < 2048; i += 256) gv[i] = lsv[i];
    int c = lcnt[tid];
    P.cnt[base + tid] = c;
    P.dinv[base + tid] = rsqrtf((float)c + 1.0f);
}

// ---- P4: agg128 over 16 nodes + fused @W2 (prescaled in/out) ----
__device__ __forceinline__ void agg128_unit(const MegaParams& P, int u, int tid,
                                            unsigned char* smem) {
    unsigned short* ys = (unsigned short*)smem;         // 16 x 136
    float* ldi = (float*)(smem + 16 * 136 * 2);
    int w = tid >> 6, lane = tid & 63;
    int half = lane >> 5, l32 = lane & 31;
    int gbase = u * 16;
    const uint2* hp2 = (const uint2*)P.hs1r;

#pragma unroll
    for (int pp = 0; pp < 2; ++pp) {
        int lrow = w * 4 + pp * 2;
        int node = gbase + lrow + half;
        int c = P.cnt[node]; if (c > SLAB) c = SLAB;
        int dm = c; int o = __shfl_xor(dm, 32); if (o > dm) dm = o;
        const unsigned short* cp = &P.col[(size_t)node * SLAB];
        float di = P.dinv[node];
        int h0 = node < P.n ? node : P.n;
        uint2 su = hp2[(size_t)h0 * 32 + l32];  // prescaled row
        float a0 = bf16_lo(su.x), a1 = bf16_hi(su.x);
        float a2 = bf16_lo(su.y), a3 = bf16_hi(su.y);

        for (int i = 0; i < dm; i += 16) {
            uint4 cA = *(const uint4*)&cp[i];
            uint4 cB = *(const uint4*)&cp[i + 8];
            unsigned ci[16];
            UNPK16(cA, cB, ci)
            uint2 uu[16];
#pragma unroll
            for (int j = 0; j < 16; ++j) uu[j] = hp2[(size_t)ci[j] * 32 + l32];
#pragma unroll
            for (int j = 0; j < 16; ++j) {
                a0 += bf16_lo(uu[j].x); a1 += bf16_hi(uu[j].x);
                a2 += bf16_lo(uu[j].y); a3 += bf16_hi(uu[j].y);
            }
        }
        float4 bv = *(const float4*)&P.b1[l32 * 4];
        float v0 = fmaxf(di * a0 + bv.x, 0.0f);
        float v1 = fmaxf(di * a1 + bv.y, 0.0f);
        float v2 = fmaxf(di * a2 + bv.z, 0.0f);
        float v3 = fmaxf(di * a3 + bv.w, 0.0f);
        *(uint2*)((char*)ys + (size_t)(lrow + half) * 272 + l32 * 8) =
            make_uint2((unsigned)f2bf(v0) | ((unsigned)f2bf(v1) << 16),
                       (unsigned)f2bf(v2) | ((unsigned)f2bf(v3) << 16));
        if (l32 == 0) ldi[lrow + half] = di;
    }
    __syncthreads();

    int quad = lane >> 4, l16 = lane & 15;
    bf16x8 a[4];
#pragma unroll
    for (int kb = 0; kb < 4; ++kb)
        a[kb] = *(const bf16x8*)&ys[l16 * 136 + kb * 32 + quad * 8];
    f32x4 acc = {0.f, 0.f, 0.f, 0.f};
#pragma unroll
    for (int kb = 0; kb < 4; ++kb) {
        bf16x8 bf = *(const bf16x8*)&P.W2T[(size_t)(w * 16 + l16) * 128 + kb * 32 + quad * 8];
        acc = __builtin_amdgcn_mfma_f32_16x16x32_bf16(a[kb], bf, acc, 0, 0, 0);
    }
#pragma unroll
    for (int r = 0; r < 4; ++r) {
        int lrow = quad * 4 + r;
        int row = gbase + lrow;
        if (row < P.n)
            P.hs2[(size_t)row * 64 + w * 16 + l16] = f2bf(acc[r] * ldi[lrow]);
    }
}

// ---- P5: agg64 over 16 nodes + fused FC head -> fp32 out ----
__device__ __forceinline__ void agg64_unit(const MegaParams& P, int u, int tid,
                                           unsigned char* smem) {
    unsigned short* yt = (unsigned short*)smem;         // 16 x 72
    int w = tid >> 6, lane = tid & 63;
    int half = lane >> 5, l32 = lane & 31;
    int gbase = u * 16;
    const unsigned* hp = (const unsigned*)P.hs2;

#pragma unroll
    for (int pp = 0; pp < 2; ++pp) {
        int lrow = w * 4 + pp * 2;
        int node = gbase + lrow + half;
        int c = P.cnt[node]; if (c > SLAB) c = SLAB;
        int dm = c; int o = __shfl_xor(dm, 32); if (o > dm) dm = o;
        const unsigned short* cp = &P.col[(size_t)node * SLAB];
        float di = P.dinv[node];
        int h0 = node < P.n ? node : P.n;
        unsigned su = hp[(size_t)h0 * 32 + l32];  // prescaled row
        float a0 = bf16_lo(su), a1 = bf16_hi(su);

        for (int i = 0; i < dm; i += 16) {
            uint4 cA = *(const uint4*)&cp[i];
            uint4 cB = *(const uint4*)&cp[i + 8];
            unsigned ci[16];
            UNPK16(cA, cB, ci)
            unsigned uu[16];
#pragma unroll
            for (int j = 0; j < 16; ++j) uu[j] = hp[(size_t)ci[j] * 32 + l32];
#pragma unroll
            for (int j = 0; j < 16; ++j) {
                a0 += bf16_lo(uu[j]); a1 += bf16_hi(uu[j]);
            }
        }
        float2 bv = *(const float2*)&P.b2[l32 * 2];
        float v0 = fmaxf(di * a0 + bv.x, 0.0f);
        float v1 = fmaxf(di * a1 + bv.y, 0.0f);
        *(unsigned*)((char*)yt + (size_t)(lrow + half) * 144 + l32 * 4) =
            (unsigned)f2bf(v0) | ((unsigned)f2bf(v1) << 16);
    }
    __syncthreads();

    int quad = lane >> 4, l16 = lane & 15;
    bf16x8 a[2];
#pragma unroll
    for (int kb = 0; kb < 2; ++kb)
        a[kb] = *(const bf16x8*)&yt[l16 * 72 + kb * 32 + quad * 8];
    f32x4 acc = {0.f, 0.f, 0.f, 0.f};
#pragma unroll
    for (int kb = 0; kb < 2; ++kb) {
        bf16x8 bf = *(const bf16x8*)&P.fcWT[(size_t)(w * 16 + l16) * 64 + kb * 32 + quad * 8];
        acc = __builtin_amdgcn_mfma_f32_16x16x32_bf16(a[kb], bf, acc, 0, 0, 0);
    }
    float bv = P.fcb[w * 16 + l16];
#pragma unroll
    for (int r = 0; r < 4; ++r) {
        int row = gbase + quad * 4 + r;
        if (row < P.n)
            P.out[(size_t)row * 64 + w * 16 + l16] = acc[r] + bv;
    }
}

// ---------------- the mega-kernel ----------------

__global__ __launch_bounds__(256, 4) void k_mega(MegaParams P) {
    __shared__ __align__(16) unsigned char smem[SMEM_BYTES];
    int tid = (int)threadIdx.x;
    int bid = (int)blockIdx.x;
    int nbl = (int)gridDim.x;
    int gtid = bid * 256 + tid, gstr = nbl * 256;

    // ---- P0: init (weight transposes, gcnt zero, sentinel rows) ----
    for (int j = gtid; j < 256; j += gstr) P.gcnt[j] = 0;
    for (int j = gtid; j < 28864; j += gstr) {
        if (j < 16384) {
            int m = j >> 7, k = j & 127;
            P.W1T[j] = f2bf(P.W1[k * 128 + m]);
        } else if (j < 24576) {
            int q = j - 16384;
            int m = q >> 7, k = q & 127;
            P.W2T[q] = f2bf(P.W2[k * 64 + m]);
        } else if (j < 28672) {
            int q = j - 24576;
            int m = q >> 6, k = q & 63;
            P.fcWT[q] = f2bf(P.fcW[k * 64 + m]);
        } else if (j < 28800) {
            P.hs1r[(size_t)P.n * 128 + (j - 28672)] = 0;
        } else {
            P.hs2[(size_t)P.n * 64 + (j - 28800)] = 0;
        }
    }
    __threadfence();
    cg::this_grid().sync();

    // ---- P1: gemm1 tiles (ngt) + binning chunks (nbin) ----
    int totalU = P.ngt + P.nbin;
    for (int u = bid; u < totalU; u += nbl) {
        if (u < P.ngt) gemm1_tile(P, u, tid, (unsigned short*)smem);
        else           bin_chunk(P, u - P.ngt, tid, (int*)smem);
        __syncthreads();
    }
    __threadfence();
    cg::this_grid().sync();

    // ---- P2: bucket-exclusive scatter ----
    for (int b = bid; b < P.nb; b += nbl) {
        scatter_bucket(P, b, tid, smem);
        __syncthreads();
    }
    __threadfence();
    cg::this_grid().sync();

    // ---- P3: full-grid in-place hs1r prescale by dinv ----
    {
        unsigned* hp = (unsigned*)P.hs1r;
        int tot = P.n * 64;
        for (int i = gtid; i < tot; i += gstr) {
            float sc = P.dinv[i >> 6];
            unsigned uu = hp[i];
            hp[i] = (unsigned)f2bf(sc * bf16_lo(uu)) |
                    ((unsigned)f2bf(sc * bf16_hi(uu)) << 16);
        }
    }
    __threadfence();
    cg::this_grid().sync();

    // ---- P4: layer-1 agg + fused @W2 -> hs2 (prescaled) ----
    for (int u = bid; u < P.nagg; u += nbl) {
        agg128_unit(P, u, tid, smem);
        __syncthreads();
    }
    __threadfence();
    cg::this_grid().sync();

    // ---- P5: layer-2 agg + fused FC head -> out ----
    for (int u = bid; u < P.nagg; u += nbl) {
        agg64_unit(P, u, tid, smem);
        __syncthreads();
    }
}

// ---------------- launch ----------------

extern "C" void kernel_launch(void* const* d_in, const int* in_sizes, int n_in,
                              void* d_out, int out_size, void* d_ws, size_t ws_size,
                              hipStream_t stream) {
    const float* x   = (const float*)d_in[0];
    const int*   ei  = (const int*)d_in[1];
    const float* W1  = (const float*)d_in[2];
    const float* b1  = (const float*)d_in[3];
    const float* W2  = (const float*)d_in[4];
    const float* b2  = (const float*)d_in[5];
    const float* fcW = (const float*)d_in[6];
    const float* fcb = (const float*)d_in[7];
    float* out = (float*)d_out;

    const int N = in_sizes[0] / 128;
    const int E = in_sizes[1] / 2;

    const int NB    = (N + 255) >> 8;
    const int Npad  = NB << 8;
    const int nbin  = (E + BINCH - 1) / BINCH;
    const int ngt   = (N + 63) / 64;
    const int nagg  = (N + 15) / 16;

    // ---- workspace carve (16B-aligned), peak ~31 MB ----
    auto align16 = [](size_t v) { return (v + 15) & ~(size_t)15; };
    char* p = (char*)d_ws;
    int* gcnt = (int*)p;                       p += align16(sizeof(int) * 256);
    unsigned* staging = (unsigned*)p;          p += align16(sizeof(unsigned) * (size_t)NB * BCAP);
    int* cnt = (int*)p;                        p += align16(sizeof(int) * Npad);
    float* dinv = (float*)p;                   p += align16(sizeof(float) * Npad);
    unsigned short* col = (unsigned short*)p;  p += align16(sizeof(unsigned short) * (size_t)Npad * SLAB);
    unsigned short* W1T = (unsigned short*)p;  p += align16(2 * 128 * 128);
    unsigned short* W2T = (unsigned short*)p;  p += align16(2 * 64 * 128);
    unsigned short* fcWT = (unsigned short*)p; p += align16(2 * 64 * 64);
    unsigned short* hs1r = (unsigned short*)p; p += align16(2 * ((size_t)N + 1) * 128);
    unsigned short* hs2 = (unsigned short*)p;  p += align16(2 * ((size_t)N + 1) * 64);

    MegaParams P;
    P.src = ei; P.dst = ei + E;
    P.e = E; P.n = N; P.nb = NB; P.nbin = nbin; P.ngt = ngt; P.nagg = nagg;
    P.gcnt = gcnt; P.staging = staging; P.cnt = cnt; P.dinv = dinv; P.col = col;
    P.x = x; P.W1 = W1; P.W2 = W2; P.fcW = fcW;
    P.b1 = b1; P.b2 = b2; P.fcb = fcb;
    P.W1T = W1T; P.W2T = W2T; P.fcWT = fcWT;
    P.hs1r = hs1r; P.hs2 = hs2; P.out = out;

    // cooperative grid: occupancy-checked blocks/CU (expect 4 -> 1024 blocks)
    static int gridBlocks = 0;
    if (gridBlocks == 0) {
        int occ = 0;
        hipOccupancyMaxActiveBlocksPerMultiprocessor(
            &occ, reinterpret_cast<const void*>(k_mega), 256, 0);
        if (occ < 1) occ = 1;
        if (occ > 4) occ = 4;
        gridBlocks = occ * 256;  // 256 CUs on MI355X
    }

    void* args[] = { (void*)&P };
    hipLaunchCooperativeKernel(reinterpret_cast<const void*>(k_mega),
                               dim3(gridBlocks), dim3(256), args, 0, stream);
}

// Round 7
// 186.983 us; speedup vs baseline: 3.9703x; 3.9703x over previous
//
#include <hip/hip_runtime.h>
#include <hip/hip_bf16.h>

// GCN_85804856639970 — 2-layer GCN + FC head, MI355X.
// N=50000, E=800000, 128->128->64, head 64x64. fp32 in/out, edge_index int32.
//
// R19 = R17 (176 us, proven) consolidated to 4 dispatches. R18 post-mortem:
// cooperative grid.sync costs ~100 us each on this 8-XCD chip (742 us total,
// VALU 2.5%) -> mega-kernel abandoned; dispatch-count reduction must come from
// ordinary fusion. Changes vs R17:
//  (1) k_wt dispatch removed: each gemm1 block transposes W1 into its own LDS
//      with XOR swizzle (wlds[m][k ^ ((m&7)<<3)] -> bank-floor ds_read_b128
//      B-fragments); W2T/fcWT/sentinel init moved into the first bin block
//      (consumed only at D3/D4).
//  (2) binning loses ALL global atomics: deterministic staging slot [c][b]
//      (SCAP=160, mean 68, +11sigma) + bincnt[c][b] fully rewritten every
//      launch (no memset, graph-replay safe); staging single-writer regions.
//  (3) D1 grid exactly machine-sized: 391 two-tile gemm blocks (68KB LDS,
//      2/CU) + 60 bin chunks co-resident.
// D2 scatter (+dinv +hs1r prescale) and D3/D4 dual-pair aggs = R17 verbatim.
// Requires N <= 65535 (16-bit ids incl. sentinel N), nbin <= 64.

typedef __attribute__((ext_vector_type(8))) short bf16x8;
typedef __attribute__((ext_vector_type(4))) float f32x4;

#define SLAB 64    // per-node adjacency capacity (max observed deg ~45)
#define SCAP 160   // staging capacity per (chunk,bucket) cell (mean 68, +11s)
#define NBIN 60    // edge chunks (grid: 391 gemm + 60 bin = 451 co-resident)

__device__ __forceinline__ unsigned short f2bf(float f) {
    unsigned u = __float_as_uint(f);
    unsigned r = (u + 0x7FFFu + ((u >> 16) & 1u)) >> 16;
    return (unsigned short)r;
}
__device__ __forceinline__ float bf16_lo(unsigned u) {
    return __uint_as_float((u & 0xFFFFu) << 16);
}
__device__ __forceinline__ float bf16_hi(unsigned u) {
    return __uint_as_float(u & 0xFFFF0000u);
}

#define UNPK16(cA, cB, ci)                                        \
    ci[0] = cA.x & 0xFFFFu;  ci[1] = cA.x >> 16;                  \
    ci[2] = cA.y & 0xFFFFu;  ci[3] = cA.y >> 16;                  \
    ci[4] = cA.z & 0xFFFFu;  ci[5] = cA.z >> 16;                  \
    ci[6] = cA.w & 0xFFFFu;  ci[7] = cA.w >> 16;                  \
    ci[8] = cB.x & 0xFFFFu;  ci[9] = cB.x >> 16;                  \
    ci[10] = cB.y & 0xFFFFu; ci[11] = cB.y >> 16;                 \
    ci[12] = cB.z & 0xFFFFu; ci[13] = cB.z >> 16;                 \
    ci[14] = cB.w & 0xFFFFu; ci[15] = cB.w >> 16;

// ---------------- D1: gemm1 (2 tiles/block, W1 in swizzled LDS) + binning ----------------

__global__ __launch_bounds__(512) void k_front(
    const int* __restrict__ src, const int* __restrict__ dst, int e,
    unsigned* __restrict__ staging, int* __restrict__ bincnt,
    const float* __restrict__ x, const float* __restrict__ W1,
    const float* __restrict__ W2, const float* __restrict__ fcW,
    unsigned short* __restrict__ W2T, unsigned short* __restrict__ fcWT,
    unsigned short* __restrict__ hs1r, unsigned short* __restrict__ hs2,
    int n, int nb, int ngemm, int nbin, int binch) {
    __shared__ __align__(16) unsigned short xs2[2][64 * 136];  // 34816 B
    __shared__ __align__(16) unsigned short wlds[128 * 128];   // 32768 B, swizzled
    __shared__ int bcnt[256], bpos[256];
    int bid = (int)blockIdx.x, tid = (int)threadIdx.x;

    if (bid < ngemm) {
        // W1 -> LDS transpose, bf16, XOR-swizzled rows (guide G4: stride-256B fix)
        for (int j = tid; j < 16384; j += 512) {
            int k = j >> 7, m = j & 127;  // W1[k][m], coalesced read over m
            wlds[m * 128 + (k ^ ((m & 7) << 3))] = f2bf(W1[j]);
        }
        __syncthreads();

        constexpr int LDW = 136;
        int tile = tid >> 8, t = tid & 255;
        unsigned short* xs = xs2[tile];
        int blk = bid * 2 + tile;
        int base = blk * 64;
        for (int idx = t; idx < 64 * 32; idx += 256) {
            int r = idx >> 5, c = idx & 31;
            int row = base + r;
            float4 v = make_float4(0.f, 0.f, 0.f, 0.f);
            if (row < n) v = ((const float4*)x)[(size_t)row * 32 + c];
            unsigned short* dp = &xs[r * LDW + c * 4];
            dp[0] = f2bf(v.x); dp[1] = f2bf(v.y); dp[2] = f2bf(v.z); dp[3] = f2bf(v.w);
        }
        __syncthreads();

        int wave = t >> 6, lane = t & 63;
        int quad = lane >> 4, l16 = lane & 15;
        int rbase = wave * 16;

        bf16x8 af[4];
#pragma unroll
        for (int kb = 0; kb < 4; ++kb)
            af[kb] = *(const bf16x8*)&xs[(rbase + l16) * LDW + kb * 32 + quad * 8];

#pragma unroll
        for (int jt = 0; jt < 8; ++jt) {
            f32x4 acc = {0.f, 0.f, 0.f, 0.f};
            int m = jt * 16 + l16;
            int sw = (l16 & 7) << 3;
#pragma unroll
            for (int kb = 0; kb < 4; ++kb) {
                bf16x8 bf = *(const bf16x8*)&wlds[m * 128 + ((kb * 32 + quad * 8) ^ sw)];
                acc = __builtin_amdgcn_mfma_f32_16x16x32_bf16(af[kb], bf, acc, 0, 0, 0);
            }
#pragma unroll
            for (int r = 0; r < 4; ++r) {
                int row = base + rbase + quad * 4 + r;
                if (row < n)
                    hs1r[(size_t)row * 128 + jt * 16 + l16] = f2bf(acc[r]);
            }
        }
    } else {
        int c = bid - ngemm;
        if (c == 0) {
            // init extras (consumed at D3/D4): W2T, fcWT, sentinel rows
            for (int j = tid; j < 12480; j += 512) {
                if (j < 8192) {
                    int m = j >> 7, k = j & 127;
                    W2T[j] = f2bf(W2[k * 64 + m]);
                } else if (j < 12288) {
                    int q = j - 8192;
                    int m = q >> 6, k = q & 63;
                    fcWT[q] = f2bf(fcW[k * 64 + m]);
                } else if (j < 12416) {
                    hs1r[(size_t)n * 128 + (j - 12288)] = 0;
                } else {
                    hs2[(size_t)n * 64 + (j - 12416)] = 0;
                }
            }
        }
        for (int i = tid; i < 256; i += 512) { bcnt[i] = 0; bpos[i] = 0; }
        __syncthreads();
        int e0 = c * binch;
        int lim = e - e0; if (lim > binch) lim = binch; if (lim < 0) lim = 0;
        for (int i = tid; i < lim; i += 512)
            atomicAdd(&bcnt[dst[e0 + i] >> 8], 1);
        __syncthreads();
        for (int i = tid; i < nb; i += 512) {
            int v = bcnt[i];
            bincnt[c * nb + i] = v < SCAP ? v : SCAP;  // every cell rewritten: no zeroing
        }
        __syncthreads();
        for (int i = tid; i < lim; i += 512) {
            int d = dst[e0 + i], s = src[e0 + i];
            int b = d >> 8;
            int p = atomicAdd(&bpos[b], 1);
            if (p < SCAP)
                staging[((size_t)c * nb + b) * SCAP + p] = ((unsigned)d << 16) | (unsigned)s;
        }
    }
}

// ---------------- D2: bucket-exclusive scatter + cnt/dinv + in-place hs1 prescale ----------------

__global__ __launch_bounds__(1024) void k_scatter(
    const unsigned* __restrict__ staging, const int* __restrict__ bincnt,
    int* __restrict__ cnt, unsigned short* __restrict__ col,
    float* __restrict__ dinv, unsigned* __restrict__ hs1u, int n, int nb, int nbin) {
    __shared__ int lcnt[256];
    __shared__ __align__(16) unsigned short ls[256 * SLAB];  // 32 KB
    __shared__ float sdi[256];
    __shared__ int scnt[64];                                  // nbin <= 64
    int b = (int)blockIdx.x, t = (int)threadIdx.x;
    if (t < 256) lcnt[t] = 0;
    if (t < nbin) scnt[t] = bincnt[t * nb + b];
    unsigned sent2 = (unsigned)n | ((unsigned)n << 16);
    for (int i = t; i < 256 * SLAB / 2; i += 1024) ((unsigned*)ls)[i] = sent2;
    __syncthreads();
    int g = t >> 6, l = t & 63;  // 16 groups of 64 lanes over segments
    for (int c = g; c < nbin; c += 16) {
        int ccnt = scnt[c];
        const unsigned* seg = staging + ((size_t)c * nb + b) * SCAP;
        for (int i = l; i < ccnt; i += 64) {
            unsigned pk = seg[i];
            int dl = (int)(pk >> 16) & 255;
            int pos = atomicAdd(&lcnt[dl], 1);
            if (pos < SLAB) ls[(dl << 6) + pos] = (unsigned short)(pk & 0xFFFFu);
        }
    }
    __syncthreads();
    int base = b << 8;
    const uint4* lsv = (const uint4*)ls;
    uint4* gv = (uint4*)(col + ((size_t)base << 6));
    for (int i = t; i < 256 * SLAB / 8; i += 1024) gv[i] = lsv[i];
    if (t < 256) {
        int c = lcnt[t];
        float dv = rsqrtf((float)c + 1.0f);
        sdi[t] = dv;
        cnt[base + t] = c;            // cnt/dinv sized Npad: pad rows get c=0
        dinv[base + t] = dv;
    }
    __syncthreads();
    // in-place pre-scale of this bucket's hs1 rows (single-writer): row *= dinv
    int rows = n - base; if (rows > 256) rows = 256; if (rows < 0) rows = 0;
    unsigned* hp = hs1u + ((size_t)base << 6);  // 64 uints (128 bf16) per row
    for (int i = t; i < rows * 64; i += 1024) {
        int r = i >> 6;
        unsigned u = hp[i];
        float sc = sdi[r];
        unsigned lo = f2bf(sc * bf16_lo(u));
        unsigned hi = f2bf(sc * bf16_hi(u));
        hp[i] = lo | (hi << 16);
    }
}

// ---------------- D3: layer-1 agg (dual-pair, prescaled rows) + fused @W2 -> hs2 ----------------

__global__ __launch_bounds__(256) void k_aggg128(
    const int* __restrict__ cnt, const unsigned short* __restrict__ col,
    const unsigned short* __restrict__ hs, const float* __restrict__ dinv,
    const float* __restrict__ bias, const unsigned short* __restrict__ W2T,
    unsigned short* __restrict__ hs2, int n) {
    __shared__ __align__(16) unsigned short ys[16 * 136];
    __shared__ float ldi[16];
    int tid = (int)threadIdx.x;
    int w = tid >> 6, lane = tid & 63;
    int half = lane >> 5, l32 = lane & 31;
    int gbase = (int)blockIdx.x * 16;
    const uint2* hp2 = (const uint2*)hs;  // row = 32 x uint2 (256 B)

    int n0 = gbase + w * 4 + half;       // pair0 node for this lane
    int n1 = n0 + 2;                     // pair1 node
    int c0 = cnt[n0]; if (c0 > SLAB) c0 = SLAB;
    int c1 = cnt[n1]; if (c1 > SLAB) c1 = SLAB;
    int dm = c0 > c1 ? c0 : c1;
    int dmo = __shfl_xor(dm, 32);
    if (dmo > dm) dm = dmo;              // max over the wave's 4 nodes

    const unsigned short* cp0 = &col[(size_t)n0 * SLAB];
    const unsigned short* cp1 = &col[(size_t)n1 * SLAB];
    float di0 = dinv[n0], di1 = dinv[n1];
    int h0 = n0 < n ? n0 : n, h1 = n1 < n ? n1 : n;
    uint2 s0 = hp2[(size_t)h0 * 32 + l32];  // prescaled: di*row
    uint2 s1 = hp2[(size_t)h1 * 32 + l32];
    float a0 = bf16_lo(s0.x), a1 = bf16_hi(s0.x), a2 = bf16_lo(s0.y), a3 = bf16_hi(s0.y);
    float b0 = bf16_lo(s1.x), b1 = bf16_hi(s1.x), b2 = bf16_lo(s1.y), b3 = bf16_hi(s1.y);

    for (int i = 0; i < dm; i += 16) {
        uint4 cA0 = *(const uint4*)&cp0[i];
        uint4 cB0 = *(const uint4*)&cp0[i + 8];
        uint4 cA1 = *(const uint4*)&cp1[i];
        uint4 cB1 = *(const uint4*)&cp1[i + 8];
        unsigned ci0[16], ci1[16];
        UNPK16(cA0, cB0, ci0)
        UNPK16(cA1, cB1, ci1)
        uint2 u0[16], u1[16];
#pragma unroll
        for (int j = 0; j < 16; ++j) u0[j] = hp2[(size_t)ci0[j] * 32 + l32];
#pragma unroll
        for (int j = 0; j < 16; ++j) u1[j] = hp2[(size_t)ci1[j] * 32 + l32];
#pragma unroll
        for (int j = 0; j < 16; ++j) {
            a0 += bf16_lo(u0[j].x); a1 += bf16_hi(u0[j].x);
            a2 += bf16_lo(u0[j].y); a3 += bf16_hi(u0[j].y);
            b0 += bf16_lo(u1[j].x); b1 += bf16_hi(u1[j].x);
            b2 += bf16_lo(u1[j].y); b3 += bf16_hi(u1[j].y);
        }
    }

    float4 bv = *(const float4*)&bias[l32 * 4];
    {
        float v0 = fmaxf(di0 * a0 + bv.x, 0.0f);
        float v1 = fmaxf(di0 * a1 + bv.y, 0.0f);
        float v2 = fmaxf(di0 * a2 + bv.z, 0.0f);
        float v3 = fmaxf(di0 * a3 + bv.w, 0.0f);
        unsigned o0 = (unsigned)f2bf(v0) | ((unsigned)f2bf(v1) << 16);
        unsigned o1 = (unsigned)f2bf(v2) | ((unsigned)f2bf(v3) << 16);
        *(uint2*)((char*)ys + (size_t)(w * 4 + half) * 272 + l32 * 8) = make_uint2(o0, o1);
    }
    {
        float v0 = fmaxf(di1 * b0 + bv.x, 0.0f);
        float v1 = fmaxf(di1 * b1 + bv.y, 0.0f);
        float v2 = fmaxf(di1 * b2 + bv.z, 0.0f);
        float v3 = fmaxf(di1 * b3 + bv.w, 0.0f);
        unsigned o0 = (unsigned)f2bf(v0) | ((unsigned)f2bf(v1) << 16);
        unsigned o1 = (unsigned)f2bf(v2) | ((unsigned)f2bf(v3) << 16);
        *(uint2*)((char*)ys + (size_t)(w * 4 + 2 + half) * 272 + l32 * 8) = make_uint2(o0, o1);
    }
    if (l32 == 0) { ldi[w * 4 + half] = di0; ldi[w * 4 + 2 + half] = di1; }
    __syncthreads();

    // fused GEMM: ys(16x128) @ W2T -> hs2(16x64), scaled by dinv[row] (prescale for layer-2 agg)
    int quad = lane >> 4, l16 = lane & 15;
    bf16x8 a[4];
#pragma unroll
    for (int kb = 0; kb < 4; ++kb)
        a[kb] = *(const bf16x8*)&ys[l16 * 136 + kb * 32 + quad * 8];
    f32x4 acc = {0.f, 0.f, 0.f, 0.f};
#pragma unroll
    for (int kb = 0; kb < 4; ++kb) {
        bf16x8 bf = *(const bf16x8*)&W2T[(size_t)(w * 16 + l16) * 128 + kb * 32 + quad * 8];
        acc = __builtin_amdgcn_mfma_f32_16x16x32_bf16(a[kb], bf, acc, 0, 0, 0);
    }
#pragma unroll
    for (int r = 0; r < 4; ++r) {
        int lrow = quad * 4 + r;
        int row = gbase + lrow;
        if (row < n)
            hs2[(size_t)row * 64 + w * 16 + l16] = f2bf(acc[r] * ldi[lrow]);
    }
}

// ---------------- D4: layer-2 agg (dual-pair) + fused FC head (fp32 out) ----------------

__global__ __launch_bounds__(256) void k_aggg64(
    const int* __restrict__ cnt, const unsigned short* __restrict__ col,
    const unsigned short* __restrict__ hs, const float* __restrict__ dinv,
    const float* __restrict__ bias, const unsigned short* __restrict__ fcWT,
    const float* __restrict__ fcb, float* __restrict__ out, int n) {
    __shared__ __align__(16) unsigned short yt[16 * 72];
    int tid = (int)threadIdx.x;
    int w = tid >> 6, lane = tid & 63;
    int half = lane >> 5, l32 = lane & 31;
    int gbase = (int)blockIdx.x * 16;
    const unsigned* hp = (const unsigned*)hs;  // row = 32 x uint (128 B)

    int n0 = gbase + w * 4 + half;
    int n1 = n0 + 2;
    int c0 = cnt[n0]; if (c0 > SLAB) c0 = SLAB;
    int c1 = cnt[n1]; if (c1 > SLAB) c1 = SLAB;
    int dm = c0 > c1 ? c0 : c1;
    int dmo = __shfl_xor(dm, 32);
    if (dmo > dm) dm = dmo;

    const unsigned short* cp0 = &col[(size_t)n0 * SLAB];
    const unsigned short* cp1 = &col[(size_t)n1 * SLAB];
    float di0 = dinv[n0], di1 = dinv[n1];
    int h0 = n0 < n ? n0 : n, h1 = n1 < n ? n1 : n;
    unsigned s0 = hp[(size_t)h0 * 32 + l32];  // rows pre-scaled by src dinv
    unsigned s1 = hp[(size_t)h1 * 32 + l32];
    float a0 = bf16_lo(s0), a1 = bf16_hi(s0);
    float b0 = bf16_lo(s1), b1 = bf16_hi(s1);

    for (int i = 0; i < dm; i += 16) {
        uint4 cA0 = *(const uint4*)&cp0[i];
        uint4 cB0 = *(const uint4*)&cp0[i + 8];
        uint4 cA1 = *(const uint4*)&cp1[i];
        uint4 cB1 = *(const uint4*)&cp1[i + 8];
        unsigned ci0[16], ci1[16];
        UNPK16(cA0, cB0, ci0)
        UNPK16(cA1, cB1, ci1)
        unsigned u0[16], u1[16];
#pragma unroll
        for (int j = 0; j < 16; ++j) u0[j] = hp[(size_t)ci0[j] * 32 + l32];
#pragma unroll
        for (int j = 0; j < 16; ++j) u1[j] = hp[(size_t)ci1[j] * 32 + l32];
#pragma unroll
        for (int j = 0; j < 16; ++j) {
            a0 += bf16_lo(u0[j]); a1 += bf16_hi(u0[j]);
            b0 += bf16_lo(u1[j]); b1 += bf16_hi(u1[j]);
        }
    }

    float2 bv = *(const float2*)&bias[l32 * 2];
    {
        float v0 = fmaxf(di0 * a0 + bv.x, 0.0f);
        float v1 = fmaxf(di0 * a1 + bv.y, 0.0f);
        *(unsigned*)((char*)yt + (size_t)(w * 4 + half) * 144 + l32 * 4) =
            (unsigned)f2bf(v0) | ((unsigned)f2bf(v1) << 16);
    }
    {
        float v0 = fmaxf(di1 * b0 + bv.x, 0.0f);
        float v1 = fmaxf(di1 * b1 + bv.y, 0.0f);
        *(unsigned*)((char*)yt + (size_t)(w * 4 + 2 + half) * 144 + l32 * 4) =
            (unsigned)f2bf(v0) | ((unsigned)f2bf(v1) << 16);
    }
    __syncthreads();

    // fused head: yt(16x64) @ fcWT -> out(16x64) fp32 + fcb
    int quad = lane >> 4, l16 = lane & 15;
    bf16x8 a[2];
#pragma unroll
    for (int kb = 0; kb < 2; ++kb)
        a[kb] = *(const bf16x8*)&yt[l16 * 72 + kb * 32 + quad * 8];
    f32x4 acc = {0.f, 0.f, 0.f, 0.f};
#pragma unroll
    for (int kb = 0; kb < 2; ++kb) {
        bf16x8 bf = *(const bf16x8*)&fcWT[(size_t)(w * 16 + l16) * 64 + kb * 32 + quad * 8];
        acc = __builtin_amdgcn_mfma_f32_16x16x32_bf16(a[kb], bf, acc, 0, 0, 0);
    }
    float bv2 = fcb[w * 16 + l16];
#pragma unroll
    for (int r = 0; r < 4; ++r) {
        int row = gbase + quad * 4 + r;
        if (row < n)
            out[(size_t)row * 64 + w * 16 + l16] = acc[r] + bv2;
    }
}

// ---------------- launch ----------------

extern "C" void kernel_launch(void* const* d_in, const int* in_sizes, int n_in,
                              void* d_out, int out_size, void* d_ws, size_t ws_size,
                              hipStream_t stream) {
    const float* x   = (const float*)d_in[0];
    const int*   ei  = (const int*)d_in[1];
    const float* W1  = (const float*)d_in[2];
    const float* b1  = (const float*)d_in[3];
    const float* W2  = (const float*)d_in[4];
    const float* b2  = (const float*)d_in[5];
    const float* fcW = (const float*)d_in[6];
    const float* fcb = (const float*)d_in[7];
    float* out = (float*)d_out;

    const int N = in_sizes[0] / 128;
    const int E = in_sizes[1] / 2;
    const int* src = ei;
    const int* dst = ei + E;

    const int NB    = (N + 255) >> 8;           // 196 buckets of 256 nodes
    const int Npad  = NB << 8;                  // rows incl. bucket padding
    const int nbin  = NBIN;                     // 60 chunks
    const int binch = (E + nbin - 1) / nbin;    // 13334 edges/chunk
    const int ngt   = (N + 63) / 64;            // 782 gemm1 tiles
    const int ngemm = (ngt + 1) / 2;            // 391 two-tile blocks
    const int nagg  = (N + 15) / 16;            // 3125

    // ---- workspace carve (16B-aligned), peak ~34 MB ----
    auto align16 = [](size_t v) { return (v + 15) & ~(size_t)15; };
    char* p = (char*)d_ws;
    unsigned* staging = (unsigned*)p;          p += align16(sizeof(unsigned) * (size_t)nbin * NB * SCAP);
    int* bincnt = (int*)p;                     p += align16(sizeof(int) * (size_t)nbin * NB);
    int* cnt = (int*)p;                        p += align16(sizeof(int) * Npad);
    float* dinv = (float*)p;                   p += align16(sizeof(float) * Npad);
    unsigned short* col = (unsigned short*)p;  p += align16(sizeof(unsigned short) * (size_t)Npad * SLAB);
    unsigned short* W2T = (unsigned short*)p;  p += align16(2 * 64 * 128);
    unsigned short* fcWT = (unsigned short*)p; p += align16(2 * 64 * 64);
    unsigned short* hs1r = (unsigned short*)p; p += align16(2 * ((size_t)N + 1) * 128);
    unsigned short* hs2 = (unsigned short*)p;  p += align16(2 * ((size_t)N + 1) * 64);

    // D1: gemm1 (391 two-tile blocks) + binning (60 chunks) + init extras
    k_front<<<ngemm + nbin, 512, 0, stream>>>(src, dst, E, staging, bincnt,
                                              x, W1, W2, fcW, W2T, fcWT,
                                              hs1r, hs2, N, NB, ngemm, nbin, binch);

    // D2: bucket-exclusive scatter -> sentinel-padded col + cnt + dinv + prescale
    k_scatter<<<NB, 1024, 0, stream>>>(staging, bincnt, cnt, col, dinv,
                                       (unsigned*)hs1r, N, NB, nbin);

    // D3: layer-1 agg (dual-pair, prescaled gathers) fused with @W2 -> hs2 (prescaled)
    k_aggg128<<<nagg, 256, 0, stream>>>(cnt, col, hs1r, dinv, b1, W2T, hs2, N);

    // D4: layer-2 agg (dual-pair) fused with FC head -> out (fp32)
    k_aggg64<<<nagg, 256, 0, stream>>>(cnt, col, hs2, dinv, b2, fcWT, fcb, out, N);
}

// Round 8
// 172.343 us; speedup vs baseline: 4.3075x; 1.0849x over previous
//
#include <hip/hip_runtime.h>
#include <hip/hip_bf16.h>

// GCN_85804856639970 — 2-layer GCN + FC head, MI355X.
// N=50000, E=800000, 128->128->64, head 64x64. fp32 in/out, edge_index int32.
//
// R20 = R17 (176 us, proven) with quad-split aggs.
// R19 post-mortem: folding W1-transpose into k_front's LDS hit write-side
// bank conflicts (1.18M) + 68KB LDS -> occ 12.5%, k_front 50 us -> 187 total.
// Reverted D1/D2/k_wt to R17 verbatim (global W1T reads are coalesced+L2-hot;
// that's why k_wt+k_front was fast).
// Agg change (both layers): 16 lanes per node (quad-split) instead of
// half-wave pairs. Wave still serves 4 nodes/round with the same in-flight
// bytes/lane (16x16B = 256B), but HALF the gather instructions and HALF the
// ci-unpack VALU -> less issue-side critical path in the latency-bound regime
// (R16/R17 counters: occ 33%, BW 26-33%, VALU 26-42%). Numerics unchanged.
// Kept: two-phase single-writer CSR, gemm1||binning fusion, dinv prescale of
// hs1r/hs2 (pure-add gathers), sentinel-padded slabs, agg+GEMM epilogue fusion.
// Requires N <= 65535 (16-bit ids incl. sentinel N).

typedef __attribute__((ext_vector_type(8))) short bf16x8;
typedef __attribute__((ext_vector_type(4))) float f32x4;

#define SLAB 64    // per-node adjacency capacity (max observed deg ~45)
#define BCAP 6144  // staging capacity per 256-node bucket (mean 4096, +32 sigma)
#define BINCH 8192 // edges per phase-1 binning block

__device__ __forceinline__ unsigned short f2bf(float f) {
    unsigned u = __float_as_uint(f);
    unsigned r = (u + 0x7FFFu + ((u >> 16) & 1u)) >> 16;
    return (unsigned short)r;
}
__device__ __forceinline__ float bf16_lo(unsigned u) {
    return __uint_as_float((u & 0xFFFFu) << 16);
}
__device__ __forceinline__ float bf16_hi(unsigned u) {
    return __uint_as_float(u & 0xFFFF0000u);
}

#define UNPK16(cA, cB, ci)                                        \
    ci[0] = cA.x & 0xFFFFu;  ci[1] = cA.x >> 16;                  \
    ci[2] = cA.y & 0xFFFFu;  ci[3] = cA.y >> 16;                  \
    ci[4] = cA.z & 0xFFFFu;  ci[5] = cA.z >> 16;                  \
    ci[6] = cA.w & 0xFFFFu;  ci[7] = cA.w >> 16;                  \
    ci[8] = cB.x & 0xFFFFu;  ci[9] = cB.x >> 16;                  \
    ci[10] = cB.y & 0xFFFFu; ci[11] = cB.y >> 16;                 \
    ci[12] = cB.z & 0xFFFFu; ci[13] = cB.z >> 16;                 \
    ci[14] = cB.w & 0xFFFFu; ci[15] = cB.w >> 16;

// ---------------- weight transpose + misc init (tiny pre-dispatch) ----------------

__global__ void k_wt(const float* __restrict__ W1, const float* __restrict__ W2,
                     const float* __restrict__ fcW,
                     unsigned short* __restrict__ W1T, unsigned short* __restrict__ W2T,
                     unsigned short* __restrict__ fcWT, int* __restrict__ gcnt,
                     unsigned short* __restrict__ hs1r, unsigned short* __restrict__ hs2,
                     int n) {
    int j = blockIdx.x * blockDim.x + threadIdx.x;
    if (j < 256) gcnt[j] = 0;  // NB <= 256
    if (j < 16384) {
        int m = j >> 7, k = j & 127;
        W1T[j] = f2bf(W1[k * 128 + m]);
    } else if (j < 24576) {
        int q = j - 16384;
        int m = q >> 7, k = q & 127;
        W2T[q] = f2bf(W2[k * 64 + m]);
    } else if (j < 28672) {
        int q = j - 24576;
        int m = q >> 6, k = q & 63;
        fcWT[q] = f2bf(fcW[k * 64 + m]);
    } else if (j < 28800) {         // zero row N of hs1r (sentinel target)
        hs1r[(size_t)n * 128 + (j - 28672)] = 0;
    } else if (j < 28864) {         // zero row N of hs2
        hs2[(size_t)n * 64 + (j - 28800)] = 0;
    }
}

// ---------------- gemm1 tile body: 64 rows of bf16(X[128] @ W1[128x128]) ----------------

__device__ __forceinline__ void gemm1_body(const float* __restrict__ X,
                                           const unsigned short* __restrict__ W1T,
                                           unsigned short* __restrict__ outp,
                                           int n, int blk, int tid,
                                           unsigned short* xs) {
    constexpr int LDW = 136;
    int base = blk * 64;
    for (int idx = tid; idx < 64 * 32; idx += 256) {
        int r = idx >> 5, c = idx & 31;
        int row = base + r;
        float4 v = make_float4(0.f, 0.f, 0.f, 0.f);
        if (row < n) v = ((const float4*)X)[(size_t)row * 32 + c];
        unsigned short* dp = &xs[r * LDW + c * 4];
        dp[0] = f2bf(v.x); dp[1] = f2bf(v.y); dp[2] = f2bf(v.z); dp[3] = f2bf(v.w);
    }
    __syncthreads();

    int wave = tid >> 6, lane = tid & 63;
    int quad = lane >> 4, l16 = lane & 15;
    int rbase = wave * 16;

    bf16x8 af[4];
#pragma unroll
    for (int kb = 0; kb < 4; ++kb)
        af[kb] = *(const bf16x8*)&xs[(rbase + l16) * LDW + kb * 32 + quad * 8];

#pragma unroll
    for (int jt = 0; jt < 8; ++jt) {
        f32x4 acc = {0.f, 0.f, 0.f, 0.f};
#pragma unroll
        for (int kb = 0; kb < 4; ++kb) {
            bf16x8 bf = *(const bf16x8*)&W1T[(size_t)(jt * 16 + l16) * 128 + kb * 32 + quad * 8];
            acc = __builtin_amdgcn_mfma_f32_16x16x32_bf16(af[kb], bf, acc, 0, 0, 0);
        }
#pragma unroll
        for (int r = 0; r < 4; ++r) {
            int row = base + rbase + quad * 4 + r;
            if (row < n)
                outp[(size_t)row * 128 + jt * 16 + l16] = f2bf(acc[r]);
        }
    }
}

// ---------------- D1: gemm1 mega-blocks (4 tiles each) + edge binning ----------------

__global__ __launch_bounds__(1024) void k_front(
    const int* __restrict__ src, const int* __restrict__ dst, int e,
    int* __restrict__ gcnt, unsigned* __restrict__ staging,
    const float* __restrict__ x, const unsigned short* __restrict__ W1T,
    unsigned short* __restrict__ hs1r, int n, int nbk, int ngemm) {
    __shared__ __align__(16) unsigned short xs4[4][64 * 136];
    __shared__ int bcnt[256], bpos[256], gofs[256];
    int bid = (int)blockIdx.x, tid = (int)threadIdx.x;

    if (bid < ngemm) {
        int tile = tid >> 8;
        gemm1_body(x, W1T, hs1r, n, bid * 4 + tile, tid & 255, xs4[tile]);
    } else {
        int b0 = bid - ngemm;
        if (tid < 256) { bcnt[tid] = 0; bpos[tid] = 0; }
        __syncthreads();
        int e0 = b0 * BINCH;
        int d[8], s[8];
#pragma unroll
        for (int r = 0; r < 8; ++r) {
            int i = e0 + r * 1024 + tid;
            if (i < e) { d[r] = dst[i]; s[r] = src[i]; } else d[r] = -1;
        }
#pragma unroll
        for (int r = 0; r < 8; ++r)
            if (d[r] >= 0) atomicAdd(&bcnt[d[r] >> 8], 1);
        __syncthreads();
        if (tid < nbk) {
            int c = bcnt[tid];
            gofs[tid] = c ? atomicAdd(&gcnt[tid], c) : 0;
        }
        __syncthreads();
#pragma unroll
        for (int r = 0; r < 8; ++r) {
            if (d[r] >= 0) {
                int b = d[r] >> 8;
                int p = atomicAdd(&bpos[b], 1);
                int idx = gofs[b] + p;
                if (idx < BCAP)
                    staging[(size_t)b * BCAP + idx] =
                        ((unsigned)d[r] << 16) | (unsigned)s[r];
            }
        }
    }
}

// ---------------- D2: bucket-exclusive scatter + in-place hs1 dinv pre-scale ----------------

__global__ __launch_bounds__(1024) void k_scatter(
    const unsigned* __restrict__ staging, const int* __restrict__ gcnt,
    int* __restrict__ cnt, unsigned short* __restrict__ col,
    float* __restrict__ dinv, unsigned* __restrict__ hs1u, int n) {
    __shared__ int lcnt[256];
    __shared__ __align__(16) unsigned short ls[256 * SLAB];  // 32 KB
    __shared__ float sdi[256];
    int b = (int)blockIdx.x, t = (int)threadIdx.x;
    if (t < 256) lcnt[t] = 0;
    unsigned sent2 = (unsigned)n | ((unsigned)n << 16);
    for (int i = t; i < 256 * SLAB / 2; i += 1024) ((unsigned*)ls)[i] = sent2;
    __syncthreads();
    int eb = gcnt[b]; if (eb > BCAP) eb = BCAP;
    const unsigned* sp = staging + (size_t)b * BCAP;
    for (int i = t; i < eb; i += 1024) {
        unsigned pk = sp[i];
        int dl = (int)(pk >> 16) & 255;
        int pos = atomicAdd(&lcnt[dl], 1);
        if (pos < SLAB) ls[(dl << 6) + pos] = (unsigned short)(pk & 0xFFFFu);
    }
    __syncthreads();
    int base = b << 8;
    const uint4* lsv = (const uint4*)ls;
    uint4* gv = (uint4*)(col + ((size_t)base << 6));
    for (int i = t; i < 256 * SLAB / 8; i += 1024) gv[i] = lsv[i];
    if (t < 256) {
        int c = lcnt[t];
        float dv = rsqrtf((float)c + 1.0f);
        sdi[t] = dv;
        cnt[base + t] = c;            // cnt/dinv sized Npad: pad rows get c=0
        dinv[base + t] = dv;
    }
    __syncthreads();
    // in-place pre-scale of this bucket's hs1 rows (single-writer): row *= dinv
    int rows = n - base; if (rows > 256) rows = 256; if (rows < 0) rows = 0;
    unsigned* hp = hs1u + ((size_t)base << 6);  // 64 uints (128 bf16) per row
    for (int i = t; i < rows * 64; i += 1024) {
        int r = i >> 6;
        unsigned u = hp[i];
        float sc = sdi[r];
        unsigned lo = f2bf(sc * bf16_lo(u));
        unsigned hi = f2bf(sc * bf16_hi(u));
        hp[i] = lo | (hi << 16);
    }
}

// ---------------- D3: layer-1 agg (quad-split: 16 lanes/node) + fused @W2 -> hs2 ----------------
// Wave serves 4 nodes concurrently: quad q owns node gbase+w*4+q; lane covers
// row bytes [l16*16, l16*16+16). 16 uint4 gathers/lane/round (half the load
// instrs of the dual-pair form at the same in-flight bytes).

__global__ __launch_bounds__(256) void k_aggg128(
    const int* __restrict__ cnt, const unsigned short* __restrict__ col,
    const unsigned short* __restrict__ hs, const float* __restrict__ dinv,
    const float* __restrict__ bias, const unsigned short* __restrict__ W2T,
    unsigned short* __restrict__ hs2, int n) {
    __shared__ __align__(16) unsigned short ys[16 * 136];
    __shared__ float ldi[16];
    int tid = (int)threadIdx.x;
    int w = tid >> 6, lane = tid & 63;
    int q = lane >> 4, l16 = lane & 15;
    int gbase = (int)blockIdx.x * 16;
    const uint4* hp4 = (const uint4*)hs;  // row = 16 x uint4 (256 B)

    int node = gbase + w * 4 + q;
    int c = cnt[node]; if (c > SLAB) c = SLAB;
    int dm = c;
    int o = __shfl_xor(dm, 16); if (o > dm) dm = o;
    o = __shfl_xor(dm, 32); if (o > dm) dm = o;   // max over the wave's 4 nodes

    const unsigned short* cp = &col[(size_t)node * SLAB];
    float di = dinv[node];
    int h0 = node < n ? node : n;
    uint4 su = hp4[(size_t)h0 * 16 + l16];  // prescaled: di*row
    float a0 = bf16_lo(su.x), a1 = bf16_hi(su.x);
    float a2 = bf16_lo(su.y), a3 = bf16_hi(su.y);
    float a4 = bf16_lo(su.z), a5 = bf16_hi(su.z);
    float a6 = bf16_lo(su.w), a7 = bf16_hi(su.w);

    for (int i = 0; i < dm; i += 16) {
        uint4 cA = *(const uint4*)&cp[i];
        uint4 cB = *(const uint4*)&cp[i + 8];
        unsigned ci[16];
        UNPK16(cA, cB, ci)
        uint4 u[16];
#pragma unroll
        for (int j = 0; j < 16; ++j) u[j] = hp4[(size_t)ci[j] * 16 + l16];
#pragma unroll
        for (int j = 0; j < 16; ++j) {
            a0 += bf16_lo(u[j].x); a1 += bf16_hi(u[j].x);
            a2 += bf16_lo(u[j].y); a3 += bf16_hi(u[j].y);
            a4 += bf16_lo(u[j].z); a5 += bf16_hi(u[j].z);
            a6 += bf16_lo(u[j].w); a7 += bf16_hi(u[j].w);
        }
    }

    float4 bv0 = *(const float4*)&bias[l16 * 8];
    float4 bv1 = *(const float4*)&bias[l16 * 8 + 4];
    float v0 = fmaxf(di * a0 + bv0.x, 0.0f);
    float v1 = fmaxf(di * a1 + bv0.y, 0.0f);
    float v2 = fmaxf(di * a2 + bv0.z, 0.0f);
    float v3 = fmaxf(di * a3 + bv0.w, 0.0f);
    float v4 = fmaxf(di * a4 + bv1.x, 0.0f);
    float v5 = fmaxf(di * a5 + bv1.y, 0.0f);
    float v6 = fmaxf(di * a6 + bv1.z, 0.0f);
    float v7 = fmaxf(di * a7 + bv1.w, 0.0f);
    uint4 ov;
    ov.x = (unsigned)f2bf(v0) | ((unsigned)f2bf(v1) << 16);
    ov.y = (unsigned)f2bf(v2) | ((unsigned)f2bf(v3) << 16);
    ov.z = (unsigned)f2bf(v4) | ((unsigned)f2bf(v5) << 16);
    ov.w = (unsigned)f2bf(v6) | ((unsigned)f2bf(v7) << 16);
    *(uint4*)((char*)ys + (size_t)(w * 4 + q) * 272 + l16 * 16) = ov;
    if (l16 == 0) ldi[w * 4 + q] = di;
    __syncthreads();

    // fused GEMM: ys(16x128) @ W2T -> hs2(16x64), scaled by dinv[row] (prescale for layer-2 agg)
    int quad = lane >> 4, l16b = lane & 15;
    bf16x8 a[4];
#pragma unroll
    for (int kb = 0; kb < 4; ++kb)
        a[kb] = *(const bf16x8*)&ys[l16b * 136 + kb * 32 + quad * 8];
    f32x4 acc = {0.f, 0.f, 0.f, 0.f};
#pragma unroll
    for (int kb = 0; kb < 4; ++kb) {
        bf16x8 bf = *(const bf16x8*)&W2T[(size_t)(w * 16 + l16b) * 128 + kb * 32 + quad * 8];
        acc = __builtin_amdgcn_mfma_f32_16x16x32_bf16(a[kb], bf, acc, 0, 0, 0);
    }
#pragma unroll
    for (int r = 0; r < 4; ++r) {
        int lrow = quad * 4 + r;
        int row = gbase + lrow;
        if (row < n)
            hs2[(size_t)row * 64 + w * 16 + l16b] = f2bf(acc[r] * ldi[lrow]);
    }
}

// ---------------- D4: layer-2 agg (quad-split) + fused FC head (fp32 out) ----------------

__global__ __launch_bounds__(256) void k_aggg64(
    const int* __restrict__ cnt, const unsigned short* __restrict__ col,
    const unsigned short* __restrict__ hs, const float* __restrict__ dinv,
    const float* __restrict__ bias, const unsigned short* __restrict__ fcWT,
    const float* __restrict__ fcb, float* __restrict__ out, int n) {
    __shared__ __align__(16) unsigned short yt[16 * 72];
    int tid = (int)threadIdx.x;
    int w = tid >> 6, lane = tid & 63;
    int q = lane >> 4, l16 = lane & 15;
    int gbase = (int)blockIdx.x * 16;
    const uint2* hp2 = (const uint2*)hs;  // row = 16 x uint2 (128 B)

    int node = gbase + w * 4 + q;
    int c = cnt[node]; if (c > SLAB) c = SLAB;
    int dm = c;
    int o = __shfl_xor(dm, 16); if (o > dm) dm = o;
    o = __shfl_xor(dm, 32); if (o > dm) dm = o;

    const unsigned short* cp = &col[(size_t)node * SLAB];
    float di = dinv[node];
    int h0 = node < n ? node : n;
    uint2 su = hp2[(size_t)h0 * 16 + l16];  // rows pre-scaled by src dinv
    float a0 = bf16_lo(su.x), a1 = bf16_hi(su.x);
    float a2 = bf16_lo(su.y), a3 = bf16_hi(su.y);

    for (int i = 0; i < dm; i += 16) {
        uint4 cA = *(const uint4*)&cp[i];
        uint4 cB = *(const uint4*)&cp[i + 8];
        unsigned ci[16];
        UNPK16(cA, cB, ci)
        uint2 u[16];
#pragma unroll
        for (int j = 0; j < 16; ++j) u[j] = hp2[(size_t)ci[j] * 16 + l16];
#pragma unroll
        for (int j = 0; j < 16; ++j) {
            a0 += bf16_lo(u[j].x); a1 += bf16_hi(u[j].x);
            a2 += bf16_lo(u[j].y); a3 += bf16_hi(u[j].y);
        }
    }

    float4 bv = *(const float4*)&bias[l16 * 4];
    float v0 = fmaxf(di * a0 + bv.x, 0.0f);
    float v1 = fmaxf(di * a1 + bv.y, 0.0f);
    float v2 = fmaxf(di * a2 + bv.z, 0.0f);
    float v3 = fmaxf(di * a3 + bv.w, 0.0f);
    uint2 ov;
    ov.x = (unsigned)f2bf(v0) | ((unsigned)f2bf(v1) << 16);
    ov.y = (unsigned)f2bf(v2) | ((unsigned)f2bf(v3) << 16);
    *(uint2*)((char*)yt + (size_t)(w * 4 + q) * 144 + l16 * 8) = ov;
    __syncthreads();

    // fused head: yt(16x64) @ fcWT -> out(16x64) fp32 + fcb
    int quad = lane >> 4, l16b = lane & 15;
    bf16x8 a[2];
#pragma unroll
    for (int kb = 0; kb < 2; ++kb)
        a[kb] = *(const bf16x8*)&yt[l16b * 72 + kb * 32 + quad * 8];
    f32x4 acc = {0.f, 0.f, 0.f, 0.f};
#pragma unroll
    for (int kb = 0; kb < 2; ++kb) {
        bf16x8 bf = *(const bf16x8*)&fcWT[(size_t)(w * 16 + l16b) * 64 + kb * 32 + quad * 8];
        acc = __builtin_amdgcn_mfma_f32_16x16x32_bf16(a[kb], bf, acc, 0, 0, 0);
    }
    float bv2 = fcb[w * 16 + l16b];
#pragma unroll
    for (int r = 0; r < 4; ++r) {
        int row = gbase + quad * 4 + r;
        if (row < n)
            out[(size_t)row * 64 + w * 16 + l16b] = acc[r] + bv2;
    }
}

// ---------------- launch ----------------

extern "C" void kernel_launch(void* const* d_in, const int* in_sizes, int n_in,
                              void* d_out, int out_size, void* d_ws, size_t ws_size,
                              hipStream_t stream) {
    const float* x   = (const float*)d_in[0];
    const int*   ei  = (const int*)d_in[1];
    const float* W1  = (const float*)d_in[2];
    const float* b1  = (const float*)d_in[3];
    const float* W2  = (const float*)d_in[4];
    const float* b2  = (const float*)d_in[5];
    const float* fcW = (const float*)d_in[6];
    const float* fcb = (const float*)d_in[7];
    float* out = (float*)d_out;

    const int N = in_sizes[0] / 128;
    const int E = in_sizes[1] / 2;
    const int* src = ei;
    const int* dst = ei + E;

    const int NB    = (N + 255) >> 8;          // 196 buckets of 256 nodes
    const int Npad  = NB << 8;                 // rows incl. bucket padding
    const int nbin  = (E + BINCH - 1) / BINCH; // 98
    const int gg64  = (N + 63) / 64;           // 782 gemm1 tiles
    const int ngemm = (gg64 + 3) / 4;          // 196 mega-blocks
    const int nagg  = (N + 15) / 16;           // 3125

    // ---- workspace carve (16B-aligned), peak ~31 MB ----
    auto align16 = [](size_t v) { return (v + 15) & ~(size_t)15; };
    char* p = (char*)d_ws;
    int* gcnt = (int*)p;                       p += align16(sizeof(int) * 256);
    unsigned* staging = (unsigned*)p;          p += align16(sizeof(unsigned) * (size_t)NB * BCAP);
    int* cnt = (int*)p;                        p += align16(sizeof(int) * Npad);
    float* dinv = (float*)p;                   p += align16(sizeof(float) * Npad);
    unsigned short* col = (unsigned short*)p;  p += align16(sizeof(unsigned short) * (size_t)Npad * SLAB);
    unsigned short* W1T = (unsigned short*)p;  p += align16(2 * 128 * 128);
    unsigned short* W2T = (unsigned short*)p;  p += align16(2 * 64 * 128);
    unsigned short* fcWT = (unsigned short*)p; p += align16(2 * 64 * 64);
    unsigned short* hs1r = (unsigned short*)p; p += align16(2 * ((size_t)N + 1) * 128);
    unsigned short* hs2 = (unsigned short*)p;  p += align16(2 * ((size_t)N + 1) * 64);

    // init: weights transpose, gcnt zero, sentinel rows
    k_wt<<<114, 256, 0, stream>>>(W1, W2, fcW, W1T, W2T, fcWT, gcnt,
                                  hs1r, hs2, N);

    // D1: gemm1 (196 mega-blocks, dispatched first) + binning (98)
    k_front<<<ngemm + nbin, 1024, 0, stream>>>(src, dst, E, gcnt, staging,
                                               x, W1T, hs1r, N, NB, ngemm);
    // D2: bucket-exclusive scatter -> sentinel-padded col + cnt + dinv,
    //     then in-place dinv pre-scale of this bucket's hs1 rows
    k_scatter<<<NB, 1024, 0, stream>>>(staging, gcnt, cnt, col, dinv,
                                       (unsigned*)hs1r, N);

    // D3: layer-1 agg (quad-split, prescaled gathers) fused with @W2 -> hs2 (prescaled)
    k_aggg128<<<nagg, 256, 0, stream>>>(cnt, col, hs1r, dinv, b1, W2T, hs2, N);

    // D4: layer-2 agg (quad-split) fused with FC head -> out (fp32)
    k_aggg64<<<nagg, 256, 0, stream>>>(cnt, col, hs2, dinv, b2, fcWT, fcb, out, N);
}